// Round 3
// baseline (115.217 us; speedup 1.0000x reference)
//
#include <hip/hip_runtime.h>
#include <math.h>

#define N      512
#define RNUM   4
#define BNUM   2
#define NSLICE (RNUM * BNUM)
#define TILE   128               // (a,b) tile 128x128, 256 threads x (8x8)
#define CT     32                // c-chunk per LDS stage (f16 tiles)
#define LSTR   136               // f16 row stride (272 B = 17*16B) - bank-verified
#define CSPLIT 16                // c-split -> 2048 main blocks
#define NCOLB  16                // colsum-role blocks (8 slices x 2 halves)
#define SCALE  0.0625f           // (1/2 relu-split) * (1/8 weight/(R*B))

typedef _Float16 half2_t __attribute__((ext_vector_type(2)));

__device__ __forceinline__ unsigned int h2u(half2_t h) {
  return __builtin_bit_cast(unsigned int, h);
}
__device__ __forceinline__ half2_t u2h(unsigned int u) {
  return __builtin_bit_cast(half2_t, u);
}

#if __has_builtin(__builtin_amdgcn_fdot2)
__device__ __forceinline__ float fdot2_(half2_t a, half2_t b, float c) {
  return __builtin_amdgcn_fdot2(a, b, c, false);
}
#else
__device__ __forceinline__ float fdot2_(half2_t a, half2_t b, float c) {
  return c + (float)a.x * (float)b.x + (float)a.y * (float)b.y;
}
#endif

// R11: guaranteed-minimal inner ops via VOP3P op_sel/neg modifiers.
//  pk_fnma_bl: lo/hi = fma(-a.lo, b.lo/hi, c.lo/hi)  (broadcast a.lo, negated)
//  pk_fnma_bh: lo/hi = fma(-a.hi, b.lo/hi, c.lo/hi)  (broadcast a.hi, negated)
// One instruction replaces {extract, pack-broadcast, pk_fma}.
// Non-volatile asm: participates in scheduling/reordering normally.
__device__ __forceinline__ unsigned pk_fnma_bl(unsigned a, unsigned b, unsigned c) {
  unsigned d;
  asm("v_pk_fma_f16 %0, %1, %2, %3 op_sel:[0,0,0] op_sel_hi:[0,1,1] neg_lo:[1,0,0] neg_hi:[1,0,0]"
      : "=v"(d) : "v"(a), "v"(b), "v"(c));
  return d;
}
__device__ __forceinline__ unsigned pk_fnma_bh(unsigned a, unsigned b, unsigned c) {
  unsigned d;
  asm("v_pk_fma_f16 %0, %1, %2, %3 op_sel:[1,0,0] op_sel_hi:[1,1,1] neg_lo:[1,0,0] neg_hi:[1,0,0]"
      : "=v"(d) : "v"(a), "v"(b), "v"(c));
  return d;
}

__device__ __forceinline__ float sigmoidf_(float x) {
  return 1.0f / (1.0f + __expf(-x));
}

__device__ __forceinline__ unsigned packh2(float a, float b) {
  half2_t h = {(_Float16)a, (_Float16)b};
  return h2u(h);
}

__global__ void zero_out_kernel(float* out) { out[0] = 0.0f; }

// R11 prep: one thread per (b,i,4xj): 64B contiguous logits load (4x float4),
// 16 sigmoids, per-plane 8B packed store (uint2 of 4 f16). Grid 512 blocks.
// Block 0 thread 0 zeroes the output accumulator.
__global__ __launch_bounds__(256) void prep_f16_kernel(const float* __restrict__ logits,
                                                       const int* __restrict__ masks,
                                                       _Float16* __restrict__ P,
                                                       float* __restrict__ out) {
  if (blockIdx.x == 0 && threadIdx.x == 0) out[0] = 0.0f;
  int t = blockIdx.x * 256 + threadIdx.x;      // 0 .. B*N*N/4 - 1
  int b = t >> 16;                              // / (N*N/4)
  int rem4 = t & (N * N / 4 - 1);
  int i = rem4 >> 7;                            // row
  int j4 = rem4 & 127;                          // j-group (j = 4*j4)
  const float4* Lp = ((const float4*)logits) + ((size_t)(b * N + i) * N + 4 * j4);
  float4 l0 = Lp[0], l1 = Lp[1], l2 = Lp[2], l3 = Lp[3];   // l_k = r0..r3 of j=4*j4+k
  int4 mj = *(const int4*)(masks + b * N + 4 * j4);
  float mi = (masks[b * N + i] > 0) ? 1.0f : 0.0f;
  float m0 = mi * ((mj.x > 0) ? 1.0f : 0.0f);
  float m1 = mi * ((mj.y > 0) ? 1.0f : 0.0f);
  float m2 = mi * ((mj.z > 0) ? 1.0f : 0.0f);
  float m3 = mi * ((mj.w > 0) ? 1.0f : 0.0f);
  size_t off = (size_t)i * N + 4 * j4;
  _Float16* Pb = P + (size_t)b * RNUM * N * N + off;
  {
    uint2 v = {packh2(m0 * sigmoidf_(l0.x), m1 * sigmoidf_(l1.x)),
               packh2(m2 * sigmoidf_(l2.x), m3 * sigmoidf_(l3.x))};
    *(uint2*)(Pb + 0 * (size_t)N * N) = v;
  }
  {
    uint2 v = {packh2(m0 * sigmoidf_(l0.y), m1 * sigmoidf_(l1.y)),
               packh2(m2 * sigmoidf_(l2.y), m3 * sigmoidf_(l3.y))};
    *(uint2*)(Pb + 1 * (size_t)N * N) = v;
  }
  {
    uint2 v = {packh2(m0 * sigmoidf_(l0.z), m1 * sigmoidf_(l1.z)),
               packh2(m2 * sigmoidf_(l2.z), m3 * sigmoidf_(l3.z))};
    *(uint2*)(Pb + 2 * (size_t)N * N) = v;
  }
  {
    uint2 v = {packh2(m0 * sigmoidf_(l0.w), m1 * sigmoidf_(l1.w)),
               packh2(m2 * sigmoidf_(l2.w), m3 * sigmoidf_(l3.w))};
    *(uint2*)(Pb + 3 * (size_t)N * N) = v;
  }
}

// Work kernel (f16 path), two roles by blockIdx.x:
//  bid <  NCOLB : colsum role — Sum_c csum_c*(N-csum_c)  (factorized Sum(t))
//  bid >= NCOLB : main role — Sum |rab - a_c*b_c|.
//
// R11 journal: wall time invariant to occupancy (R0/R1/R2: 60.5/63.6/59.4 at
// 8/4/8 waves-SIMD) => issue-bound, raw VALUBusy (~70%) believed CORRECT =>
// ~42us real VALU vs 21us essential = 2x inner-loop bloat. Fix:
//  * inline-asm v_pk_fma_f16 with op_sel broadcast + neg (1 inst/pair does
//    broadcast+negate+fma; no codegen roulette).
//  * accumulate |t| with v_pk_add_f16 (full-rate) into q[x]; dot2 only to
//    FLUSH every 4 c's (dot2 count /8 — hedges slow-dot2 hypothesis).
//    Flush-group half-sums <= 16: f16 rounding ~1e-7 relative on final.
//  * __launch_bounds__(256,4): 128-VGPR tier. rabw 32 + q 8 + acc 8 +
//    tiles 8 + addr ~ 85 — no spill, ds_reads hoistable (VGPR 28-32 builds
//    could not hoist: serialized lgkmcnt waits). R1 proved 4 waves/SIMD
//    costs <=7%.
//  * inner loop = exactly 3 VALU/pair: pk_fma(asm) + v_and + pk_add.
__global__ __launch_bounds__(256, 4) void work_f16_kernel(const _Float16* __restrict__ P,
                                                          float* __restrict__ out) {
  __shared__ __align__(16) _Float16 tA[CT][LSTR];
  __shared__ __align__(16) _Float16 tB[CT][LSTR];
  __shared__ float wsum[4];

  const int tid = threadIdx.x;
  const int bid = blockIdx.x;

  if (bid < NCOLB) {
    // ---- colsum role ----
    const int s    = bid >> 1;
    const int half = bid & 1;
    const int c    = half * 256 + tid;
    const _Float16* col = P + (size_t)s * N * N + c;
    float sum = 0.0f;
#pragma unroll 16
    for (int a = 0; a < N; ++a) sum += (float)col[(size_t)a * N];
    float v = sum * ((float)N - sum);
    for (int off = 32; off > 0; off >>= 1) v += __shfl_down(v, off, 64);
    const int wid = tid >> 6;
    if ((tid & 63) == 0) wsum[wid] = v;
    __syncthreads();
    if (tid == 0)
      atomicAdd(out, (wsum[0] + wsum[1] + wsum[2] + wsum[3]) * SCALE);
    return;
  }

  // ---- main role ----
  const int m  = bid - NCOLB;
  const int bt = m & 3;
  const int at = (m >> 2) & 3;
  const int s  = (m >> 4) & 7;
  const int cz = m >> 7;                    // 0..CSPLIT-1
  const int a0 = at * TILE;
  const int b0 = bt * TILE;
  const int c0 = cz * CT;                   // exactly one CT-chunk per block

  const int ta = tid & 15;    // a cols: a0 + ta*8 + {0..7}
  const int tb = tid >> 4;    // b cols: b0 + tb*8 + {0..7}

  const _Float16* Ph = P + (size_t)s * N * N;

  // staging: thread transposes a ROW-PAIR (2 rows) x 16 c's, packing
  // {row0[c],row1[c]} u32 into LDS column pair (2p, 2p+1).
  {
    const int u   = tid & 127;
    const int h   = tid >> 7;
    const int isB = u >> 6;
    const int p   = u & 63;                 // pair index within tile
    const int r0  = (isB ? b0 : a0) + 2 * p;
    const int cc0 = c0 + h * 16;
    const _Float16* s0row = Ph + (size_t)r0 * N + cc0;
    const _Float16* s1row = s0row + N;
    _Float16* dst = isB ? &tB[h * 16][2 * p] : &tA[h * 16][2 * p];
    uint4 q0 = ((const uint4*)s0row)[0];
    uint4 q1 = ((const uint4*)s0row)[1];
    uint4 r0v = ((const uint4*)s1row)[0];
    uint4 r1v = ((const uint4*)s1row)[1];
    unsigned int w0[8] = {q0.x, q0.y, q0.z, q0.w, q1.x, q1.y, q1.z, q1.w};
    unsigned int w1[8] = {r0v.x, r0v.y, r0v.z, r0v.w, r1v.x, r1v.y, r1v.z, r1v.w};
#pragma unroll
    for (int k = 0; k < 8; ++k) {
      unsigned int lo = (w1[k] << 16) | (w0[k] & 0xFFFFu);       // c = 2k
      unsigned int hi = (w1[k] & 0xFFFF0000u) | (w0[k] >> 16);   // c = 2k+1
      *(unsigned int*)(dst + (size_t)(2 * k) * LSTR)     = lo;
      *(unsigned int*)(dst + (size_t)(2 * k + 1) * LSTR) = hi;
    }
  }

  // rab tile as packed u32: rabw[x][yp] = {rab[x][2yp], rab[x][2yp+1]}
  unsigned rabw[8][4];
#pragma unroll
  for (int x = 0; x < 8; ++x) {
    int ga = a0 + ta * 8 + x;
    uint4 q = *(const uint4*)(Ph + (size_t)ga * N + b0 + tb * 8);
    rabw[x][0] = q.x; rabw[x][1] = q.y; rabw[x][2] = q.z; rabw[x][3] = q.w;
  }

  float acc[8];
  unsigned q16[8];
#pragma unroll
  for (int x = 0; x < 8; ++x) { acc[x] = 0.0f; q16[x] = 0u; }

  const half2_t kOne = {(_Float16)1.0f, (_Float16)1.0f};

  __syncthreads();

#pragma unroll 1
  for (int cg = 0; cg < CT / 4; ++cg) {
#pragma unroll
    for (int dc = 0; dc < 4; ++dc) {
      const int c = cg * 4 + dc;
      uint4 ua = *(const uint4*)&tA[c][ta * 8];   // 8 a-vals (b128, conflict-free)
      uint4 ub = *(const uint4*)&tB[c][tb * 8];   // 8 b-vals (16-lane broadcast)
      unsigned aw[4] = {ua.x, ua.y, ua.z, ua.w};
      unsigned bw[4] = {ub.x, ub.y, ub.z, ub.w};
#pragma unroll
      for (int k = 0; k < 4; ++k) {
#pragma unroll
        for (int yp = 0; yp < 4; ++yp) {
          unsigned tl = pk_fnma_bl(aw[k], bw[yp], rabw[2 * k][yp]);
          q16[2 * k] = h2u(u2h(q16[2 * k]) + u2h(tl & 0x7FFF7FFFu));
          unsigned th = pk_fnma_bh(aw[k], bw[yp], rabw[2 * k + 1][yp]);
          q16[2 * k + 1] = h2u(u2h(q16[2 * k + 1]) + u2h(th & 0x7FFF7FFFu));
        }
      }
    }
    // flush packed f16 partials (half-sums <= 16) into f32
#pragma unroll
    for (int x = 0; x < 8; ++x) {
      acc[x] = fdot2_(u2h(q16[x]), kOne, acc[x]);
      q16[x] = 0u;
    }
  }

  float tsum = 0.0f;
#pragma unroll
  for (int x = 0; x < 8; ++x) tsum += acc[x];

  for (int off = 32; off > 0; off >>= 1) tsum += __shfl_down(tsum, off, 64);

  const int wid = tid >> 6;
  if ((tid & 63) == 0) wsum[wid] = tsum;
  __syncthreads();
  if (tid == 0)
    atomicAdd(out, (wsum[0] + wsum[1] + wsum[2] + wsum[3]) * SCALE);
}

// ---------------- f32 fallback (no workspace): R4 structure ----------------
#define FCT    64
#define FSTR   132
#define FCSPL  4

__global__ __launch_bounds__(256, 2) void work_f32_fallback(const float* __restrict__ logits,
                                                            const int* __restrict__ masks,
                                                            float* __restrict__ out) {
  __shared__ __align__(16) float tA[FCT][FSTR];
  __shared__ __align__(16) float tB[FCT][FSTR];
  __shared__ float wsum[4];

  const int tid = threadIdx.x;
  const int bid = blockIdx.x;

  if (bid < NCOLB) {
    const int s    = bid >> 1;
    const int half = bid & 1;
    const int c    = half * 256 + tid;
    const int bb   = s >> 2;
    const int r    = s & 3;
    const int* mrow = masks + bb * N;
    float mc = (mrow[c] > 0) ? 1.0f : 0.0f;
    float sum = 0.0f;
#pragma unroll 4
    for (int a = 0; a < N; ++a) {
      float ma = (mrow[a] > 0) ? 1.0f : 0.0f;
      size_t idx = ((size_t)(bb * N + a) * N + c) * RNUM + r;
      sum += sigmoidf_(logits[idx]) * ma * mc;
    }
    float v = sum * ((float)N - sum);
    for (int off = 32; off > 0; off >>= 1) v += __shfl_down(v, off, 64);
    const int wid = tid >> 6;
    if ((tid & 63) == 0) wsum[wid] = v;
    __syncthreads();
    if (tid == 0)
      atomicAdd(out, (wsum[0] + wsum[1] + wsum[2] + wsum[3]) * SCALE);
    return;
  }

  const int m  = bid - NCOLB;
  const int bt = m & 3;
  const int at = (m >> 2) & 3;
  const int s  = (m >> 4) & 7;
  const int cz = m >> 7;
  const int a0 = at * TILE;
  const int b0 = bt * TILE;
  const int bb = s >> 2;
  const int r  = s & 3;
  const int cbeg = cz * (N / FCSPL);
  const int cend = cbeg + (N / FCSPL);

  const int ta = tid & 15;
  const int tb = tid >> 4;
  const int* mrow = masks + bb * N;

  float rab[8][8];
#pragma unroll
  for (int x = 0; x < 8; ++x) {
    int ra = a0 + ((x >> 2) << 6) + ta * 4 + (x & 3);
    float ma = (mrow[ra] > 0) ? 1.0f : 0.0f;
#pragma unroll
    for (int y = 0; y < 8; ++y) {
      int cb = b0 + ((y >> 2) << 6) + tb * 4 + (y & 3);
      float mb = (mrow[cb] > 0) ? 1.0f : 0.0f;
      size_t idx = ((size_t)(bb * N + ra) * N + cb) * RNUM + r;
      rab[x][y] = sigmoidf_(logits[idx]) * ma * mb;
    }
  }

  float acc[8][2];
#pragma unroll
  for (int x = 0; x < 8; ++x) { acc[x][0] = 0.0f; acc[x][1] = 0.0f; }

  for (int c0 = cbeg; c0 < cend; c0 += FCT) {
    __syncthreads();
#pragma unroll
    for (int it = 0; it < 32; ++it) {
      int e = it * 256 + tid;
      int c = e & 63;
      int i = e >> 6;
      int pc = ((((i >> 2) ^ ((c >> 2) & 31)) & 31) << 2) | (i & 3);
      float mc = (mrow[c0 + c] > 0) ? 1.0f : 0.0f;
      {
        float mi = (mrow[a0 + i] > 0) ? 1.0f : 0.0f;
        size_t idx = ((size_t)(bb * N + a0 + i) * N + (c0 + c)) * RNUM + r;
        tA[c][pc] = sigmoidf_(logits[idx]) * mi * mc;
      }
      {
        float mi = (mrow[b0 + i] > 0) ? 1.0f : 0.0f;
        size_t idx = ((size_t)(bb * N + b0 + i) * N + (c0 + c)) * RNUM + r;
        tB[c][pc] = sigmoidf_(logits[idx]) * mi * mc;
      }
    }
    __syncthreads();

#pragma unroll 2
    for (int cg = 0; cg < FCT / 4; ++cg) {
      const float* pa = &tA[cg * 4][((ta ^ cg) & 31) << 2];
      const float* pb = &tB[cg * 4][((tb ^ cg) & 31) << 2];
#pragma unroll
      for (int dc = 0; dc < 4; ++dc) {
        float4 a0v = *(const float4*)(pa + dc * FSTR);
        float4 a1v = *(const float4*)(pa + dc * FSTR + 64);
        float4 b0v = *(const float4*)(pb + dc * FSTR);
        float4 b1v = *(const float4*)(pb + dc * FSTR + 64);
        float avv[8] = {a0v.x, a0v.y, a0v.z, a0v.w, a1v.x, a1v.y, a1v.z, a1v.w};
        float bvv[8] = {b0v.x, b0v.y, b0v.z, b0v.w, b1v.x, b1v.y, b1v.z, b1v.w};
#pragma unroll
        for (int x = 0; x < 8; ++x) {
#pragma unroll
          for (int y = 0; y < 4; ++y)
            acc[x][0] += fabsf(fmaf(-avv[x], bvv[y], rab[x][y]));
#pragma unroll
          for (int y = 4; y < 8; ++y)
            acc[x][1] += fabsf(fmaf(-avv[x], bvv[y], rab[x][y]));
        }
      }
    }
  }

  float tsum = 0.0f;
#pragma unroll
  for (int x = 0; x < 8; ++x) tsum += acc[x][0] + acc[x][1];
  for (int off = 32; off > 0; off >>= 1) tsum += __shfl_down(tsum, off, 64);
  const int wid = tid >> 6;
  if ((tid & 63) == 0) wsum[wid] = tsum;
  __syncthreads();
  if (tid == 0)
    atomicAdd(out, (wsum[0] + wsum[1] + wsum[2] + wsum[3]) * SCALE);
}

extern "C" void kernel_launch(void* const* d_in, const int* in_sizes, int n_in,
                              void* d_out, int out_size, void* d_ws, size_t ws_size,
                              hipStream_t stream) {
  const float* logits = (const float*)d_in[0];
  const int*   masks  = (const int*)d_in[1];
  float*       out    = (float*)d_out;

  const size_t P_BYTES = (size_t)NSLICE * N * N * sizeof(_Float16);  // 4 MB

  if (ws_size >= P_BYTES) {
    _Float16* P = (_Float16*)d_ws;
    prep_f16_kernel<<<(BNUM * N * N / 4) / 256, 256, 0, stream>>>(logits, masks, P, out);
    const int nblocks = NCOLB + 4 * 4 * NSLICE * CSPLIT;  // 16 + 2048
    work_f16_kernel<<<nblocks, 256, 0, stream>>>(P, out);
  } else {
    zero_out_kernel<<<1, 1, 0, stream>>>(out);
    const int nblocks = NCOLB + 4 * 4 * NSLICE * FCSPL;   // 16 + 512
    work_f32_fallback<<<nblocks, 256, 0, stream>>>(logits, masks, out);
  }
}